// Round 3
// baseline (182.087 us; speedup 1.0000x reference)
//
#include <hip/hip_runtime.h>
#include <cstdint>

typedef _Float16 f16;
typedef _Float16 f16x4 __attribute__((ext_vector_type(4)));
typedef _Float16 f16x8 __attribute__((ext_vector_type(8)));
typedef float f32x4 __attribute__((ext_vector_type(4)));

#define MFMA16(a, b, c) __builtin_amdgcn_mfma_f32_16x16x32_f16(a, b, c, 0, 0, 0)
#define QSCALE 0.1803368801111243f  /* 0.125 * log2(e): scores land in log2 domain */

// direct global->LDS 16B async copy (m97 pattern)
__device__ __forceinline__ void gload_lds16(const void* g, void* l) {
    __builtin_amdgcn_global_load_lds((__attribute__((address_space(1))) void*)(g),
                                     (__attribute__((address_space(3))) void*)(l),
                                     16, 0, 0);
}

// Problem constants: S=2048, B=2, D=1024, H=16, DK=64
// ws layout (bytes):
//  xh   @ 0         : 4096x1024 f16 = 8 MB       (dead after gemm_qkv)
//  wqh  @ 8388608   : 3072x1024 f16 = 6 MB
//  woh  @ 14680064  : 1024x1024 f16 = 2 MB
//  qh   @ 16777216  : [32][2048][64] f16 = 8 MB  (PRE-SCALED by 0.125*log2e)
//  kh   @ 25165824  : [32][2048][64] f16 = 8 MB
//  vt   @ 33554432  : [32][64][2048] f16 = 8 MB  (V transposed, written by gemm_qkv)
//  ah   @ 41943040  : [4096][1024] f16 = 8 MB

// Single fused cast: outputs are contiguous in ws (xh | wqh | woh).
__global__ void cast_all(const float* __restrict__ x, const float* __restrict__ wqv,
                         const float* __restrict__ wo, f16* __restrict__ out) {
    int i = blockIdx.x * blockDim.x + threadIdx.x;  // 0..2097151 float4s
    const float* src; int li;
    if (i < 1048576)      { src = x;   li = i; }
    else if (i < 1835008) { src = wqv; li = i - 1048576; }
    else                  { src = wo;  li = i - 1835008; }
    float4 v = reinterpret_cast<const float4*>(src)[li];
    f16x4 o = {(f16)v.x, (f16)v.y, (f16)v.z, (f16)v.w};
    reinterpret_cast<f16x4*>(out)[i] = o;
}

// ---------------- QKV GEMM: C[4096x3072] = X[4096x1024] * Wqkv^T ----------------
// R7: 3-deep pipelined K-loop. BK=32, 3 LDS buffers (ring t%3): while computing
// tile t, tile t+2 is being staged; tile t+1 is landing. One raw s_barrier per
// tile with counted s_waitcnt vmcnt(4) (never drains the queue in steady state).
__global__ __launch_bounds__(256, 3) void gemm_qkv(
    const f16* __restrict__ A, const f16* __restrict__ B,
    f16* __restrict__ outq, f16* __restrict__ outk, f16* __restrict__ outvt)
{
    __shared__ f16 As[3][128 * 32];
    __shared__ f16 Bs[3][128 * 32];
    const int tid = threadIdx.x;
    const int lane = tid & 63;
    const int wave = tid >> 6;
    const int wm = wave >> 1, wn = wave & 1;
    const int bm = blockIdx.y * 128, bn = blockIdx.x * 128;
    const int fr = lane & 15, fq = lane >> 4;

    const int srow = tid >> 2;                                    // 0..63
    const int su = (tid & 3) ^ (srow & 3) ^ ((srow >> 2) & 3);    // swizzled src 16B-unit
    const int uoff = (fq ^ (fr & 3) ^ ((fr >> 2) & 3)) * 8;       // lane-const read offset

    f32x4 acc[4][4] = {};

    auto stg = [&](int tt, int buf) {
        const int k0 = tt * 32;
        gload_lds16(&A[(bm + srow) * 1024 + k0 + su * 8],      &As[buf][tid * 8]);
        gload_lds16(&A[(bm + 64 + srow) * 1024 + k0 + su * 8], &As[buf][2048 + tid * 8]);
        gload_lds16(&B[(bn + srow) * 1024 + k0 + su * 8],      &Bs[buf][tid * 8]);
        gload_lds16(&B[(bn + 64 + srow) * 1024 + k0 + su * 8], &Bs[buf][2048 + tid * 8]);
    };

    auto step = [&](int t, int buf) {
        const int b2 = (buf + 2 >= 3) ? (buf - 1) : (buf + 2);
        if (t < 30) stg(t + 2, b2);
        f16x8 af[4], bf[4];
#pragma unroll
        for (int mt = 0; mt < 4; ++mt)
            af[mt] = *(const f16x8*)&As[buf][(wm * 64 + mt * 16 + fr) * 32 + uoff];
#pragma unroll
        for (int nt = 0; nt < 4; ++nt)
            bf[nt] = *(const f16x8*)&Bs[buf][(wn * 64 + nt * 16 + fr) * 32 + uoff];
        __builtin_amdgcn_s_setprio(1);
#pragma unroll
        for (int mt = 0; mt < 4; ++mt)
#pragma unroll
            for (int nt = 0; nt < 4; ++nt)
                acc[mt][nt] = MFMA16(af[mt], bf[nt], acc[mt][nt]);
        __builtin_amdgcn_s_setprio(0);
        if (t < 30) { asm volatile("s_waitcnt vmcnt(4)" ::: "memory"); }
        else        { asm volatile("s_waitcnt vmcnt(0)" ::: "memory"); }
        __builtin_amdgcn_s_barrier();
        __builtin_amdgcn_sched_barrier(0);
    };

    stg(0, 0);
    stg(1, 1);
    asm volatile("s_waitcnt vmcnt(4)" ::: "memory");
    __builtin_amdgcn_s_barrier();
    __builtin_amdgcn_sched_barrier(0);
#pragma unroll 1
    for (int tb = 0; tb < 30; tb += 3) {
        step(tb, 0);
        step(tb + 1, 1);
        step(tb + 2, 2);
    }
    step(30, 0);
    step(31, 1);

    const int x = blockIdx.x;
    if (x < 16) {
        // Q (x<8) or K block: uniform target, row-layout [bh][s][64]
        f16* base = (x < 8) ? outq : outk;
        const float scale = (x < 8) ? QSCALE : 1.0f;
        const int coloff = (x < 8) ? bn : (bn - 1024);
#pragma unroll
        for (int mt = 0; mt < 4; ++mt)
#pragma unroll
            for (int nt = 0; nt < 4; ++nt)
#pragma unroll
                for (int i = 0; i < 4; ++i) {
                    int row = bm + wm * 64 + mt * 16 + fq * 4 + i;  // (s*2+b)
                    int col = coloff + wn * 64 + nt * 16 + fr;      // 0..1023
                    int s = row >> 1, b = row & 1;
                    int h = col >> 6, dk = col & 63;
                    base[((b * 16 + h) * 2048 + s) * 64 + dk] = (f16)(acc[mt][nt][i] * scale);
                }
    } else {
        // V block: LDS transpose (2 passes over wn halves) -> vt[bh][dk][s]
        const int xb = x - 16;              // 0..7
        const int s0 = bm >> 1;             // 64-aligned s base
        f16* Ts = &As[0][0];                // [128][76] = 9728 f16 (fits in As[3][4096])
#pragma unroll
        for (int p = 0; p < 2; ++p) {
            __syncthreads();
            if (wn == p) {
#pragma unroll
                for (int mt = 0; mt < 4; ++mt)
#pragma unroll
                    for (int nt = 0; nt < 4; ++nt)
#pragma unroll
                        for (int i = 0; i < 4; ++i) {
                            int row = wm * 64 + mt * 16 + fq * 4 + i;  // 0..127 local
                            int cl = nt * 16 + fr;                     // 0..63 local col
                            Ts[(cl * 2 + (row & 1)) * 76 + (row >> 1)] = (f16)acc[mt][nt][i];
                        }
            }
            __syncthreads();
            const int h = xb * 2 + p;
            const int sj = tid & 7;
#pragma unroll
            for (int it = 0; it < 4; ++it) {
                int idx = (tid >> 3) + it * 32;     // 0..127
                int bsel = idx & 1, dk = idx >> 1;  // b, dk(=cl)
                f16x8 v = *(const f16x8*)&Ts[(dk * 2 + bsel) * 76 + sj * 8];
                *(f16x8*)&outvt[((bsel * 16 + h) * 64 + dk) * 2048 + s0 + sj * 8] = v;
            }
        }
    }
}

// ---------------- Flash attention (causal) — R8: 32-row waves, swapped QK^T ----------------
// Block = 4 waves (256 thr). Waves 0-1 own 32 rows each of tile B(31-qpair); waves
// 2-3 own 32 rows each of tile A(qpair). Each wave covers 32 q-rows: K/V LDS frag
// reads are shared across its two 16-row sub-blocks -> HALF the LDS read traffic
// per q-row (attn was LDS-pipe bound: ~34us of 44.5us was ds_read).
// QK^T computed SWAPPED: mfma(K,Q) -> D[k][q]. Per-lane P slice is contiguous in k,
// so P spills to LDS as 8x ds_write_b64 (was 16x b16) and the row-sum l is a single
// scalar per lane (reduce = 2 shfl_xor). Q pre-scaled -> p = exp2(sc) directly.
__global__ __launch_bounds__(256, 2) void attn_kernel(
    const f16* __restrict__ qg, const f16* __restrict__ kg,
    const f16* __restrict__ vtg, f16* __restrict__ attn)
{
    __shared__ f16 Ks[2][64 * 64];
    __shared__ f16 Vs[2][64 * 64];
    __shared__ f16 plds[4][32 * 72];
    const int tid = threadIdx.x;
    const int lane = tid & 63;
    const int wave = tid >> 6;      // 0..3
    const int qpair = blockIdx.x;   // 0..15
    const int bh = blockIdx.y;
    const int b = bh >> 4, h = bh & 15;
    const int fr = lane & 15, fq = lane >> 4;

    const bool isB = wave < 2;
    const int w2 = wave & 1;
    const int qrow = (isB ? (31 - qpair) : qpair) * 64 + w2 * 32;  // wave's 32-row base
    const int nB = 32 - qpair;            // chunks staged by the block
    const int nK = (qrow >> 6) + 1;       // chunks this wave computes (B-waves: == nB)

    const f16* Q  = qg  + bh * 2048 * 64;
    const f16* K  = kg  + bh * 2048 * 64;
    const f16* VT = vtg + bh * 64 * 2048;
    f16* P = plds[wave];

    const int srow = tid >> 3;              // 0..31
    const int su8 = (tid & 7) ^ (srow & 7); // logical 16B-unit (pre-swizzled source)

    // Q fragments for the wave's two 16-row sub-blocks (qb0: rows qrow.., qb1: +16)
    f16x8 aq00 = *(const f16x8*)&Q[(qrow + fr) * 64 + fq * 8];
    f16x8 aq01 = *(const f16x8*)&Q[(qrow + fr) * 64 + 32 + fq * 8];
    f16x8 aq10 = *(const f16x8*)&Q[(qrow + 16 + fr) * 64 + fq * 8];
    f16x8 aq11 = *(const f16x8*)&Q[(qrow + 16 + fr) * 64 + 32 + fq * 8];

    f32x4 o[2][4] = {};
    float lsum[2] = {0.f, 0.f};

    auto stage = [&](int kc, int buf) {
        const int kb = kc * 64;
        gload_lds16(&K[(kb + srow) * 64 + su8 * 8],         &Ks[buf][tid * 8]);
        gload_lds16(&K[(kb + srow + 32) * 64 + su8 * 8],    &Ks[buf][2048 + tid * 8]);
        gload_lds16(&VT[srow * 2048 + kb + su8 * 8],        &Vs[buf][tid * 8]);
        gload_lds16(&VT[(srow + 32) * 2048 + kb + su8 * 8], &Vs[buf][2048 + tid * 8]);
    };

    auto compute = [&](int kb, const f16* Ksb, const f16* Vsb, bool domask) {
        f32x4 sc0[4] = {}, sc1[4] = {};
        // QK^T swapped: D[k_local][q_local]; K-frags shared across both q sub-blocks
#pragma unroll
        for (int ct = 0; ct < 4; ++ct) {
            int r = ct * 16 + fr;
            f16x8 kf0 = *(const f16x8*)&Ksb[r * 64 + ((fq ^ (r & 7)) * 8)];
            f16x8 kf1 = *(const f16x8*)&Ksb[r * 64 + (((4 + fq) ^ (r & 7)) * 8)];
            sc0[ct] = MFMA16(kf0, aq00, sc0[ct]);
            sc0[ct] = MFMA16(kf1, aq01, sc0[ct]);
            sc1[ct] = MFMA16(kf0, aq10, sc1[ct]);
            sc1[ct] = MFMA16(kf1, aq11, sc1[ct]);
        }
        if (domask) {
#pragma unroll
            for (int ct = 0; ct < 4; ++ct) {
                int kk = kb + ct * 16 + fq * 4;   // k index of element i is kk+i
#pragma unroll
                for (int i = 0; i < 4; ++i) {
                    if (kk + i > qrow + fr)      sc0[ct][i] = -1e30f;
                    if (kk + i > qrow + 16 + fr) sc1[ct][i] = -1e30f;
                }
            }
        }
        float l0 = 0.f, l1 = 0.f;
#pragma unroll
        for (int ct = 0; ct < 4; ++ct) {
            float p0 = __builtin_amdgcn_exp2f(sc0[ct][0]);
            float p1 = __builtin_amdgcn_exp2f(sc0[ct][1]);
            float p2 = __builtin_amdgcn_exp2f(sc0[ct][2]);
            float p3 = __builtin_amdgcn_exp2f(sc0[ct][3]);
            l0 += (p0 + p1) + (p2 + p3);
            f16x4 pk0 = {(f16)p0, (f16)p1, (f16)p2, (f16)p3};
            *(f16x4*)&P[fr * 72 + ct * 16 + fq * 4] = pk0;
            float q0 = __builtin_amdgcn_exp2f(sc1[ct][0]);
            float q1 = __builtin_amdgcn_exp2f(sc1[ct][1]);
            float q2 = __builtin_amdgcn_exp2f(sc1[ct][2]);
            float q3 = __builtin_amdgcn_exp2f(sc1[ct][3]);
            l1 += (q0 + q1) + (q2 + q3);
            f16x4 pk1 = {(f16)q0, (f16)q1, (f16)q2, (f16)q3};
            *(f16x4*)&P[(16 + fr) * 72 + ct * 16 + fq * 4] = pk1;
        }
        lsum[0] += l0;
        lsum[1] += l1;
        // PV: A-frag = P rows (q-local=fr), B-frag = V^T rows (dk); V-frags shared
        f16x8 ap00 = *(const f16x8*)&P[fr * 72 + fq * 8];
        f16x8 ap01 = *(const f16x8*)&P[fr * 72 + 32 + fq * 8];
        f16x8 ap10 = *(const f16x8*)&P[(16 + fr) * 72 + fq * 8];
        f16x8 ap11 = *(const f16x8*)&P[(16 + fr) * 72 + 32 + fq * 8];
#pragma unroll
        for (int nt = 0; nt < 4; ++nt) {
            int dk = nt * 16 + fr;
            f16x8 bv0 = *(const f16x8*)&Vsb[dk * 64 + ((fq ^ (dk & 7)) * 8)];
            f16x8 bv1 = *(const f16x8*)&Vsb[dk * 64 + (((4 + fq) ^ (dk & 7)) * 8)];
            o[0][nt] = MFMA16(ap00, bv0, o[0][nt]);
            o[0][nt] = MFMA16(ap01, bv1, o[0][nt]);
            o[1][nt] = MFMA16(ap10, bv0, o[1][nt]);
            o[1][nt] = MFMA16(ap11, bv1, o[1][nt]);
        }
    };

    stage(0, 0);
    for (int kc = 0; kc < nB; ++kc) {
        const int kb = kc * 64;
        const int cur = kc & 1;
        __syncthreads();
        if (kc + 1 < nB) stage(kc + 1, cur ^ 1);
        if (kc < nK) compute(kb, Ks[cur], Vs[cur], kb + 63 > qrow);
    }

#pragma unroll
    for (int qb = 0; qb < 2; ++qb) {
        // lane (fr,fq) holds partial sum for q-row qrow+qb*16+fr over its k-slices
        float rs = lsum[qb];
        rs += __shfl_xor(rs, 16);
        rs += __shfl_xor(rs, 32);
        float inv = __builtin_amdgcn_rcpf(rs);
#pragma unroll
        for (int i = 0; i < 4; ++i) {
            float invi = __shfl(inv, fq * 4 + i);   // inv for q-local16 = fq*4+i
            int srow = qrow + qb * 16 + fq * 4 + i;
#pragma unroll
            for (int nt = 0; nt < 4; ++nt)
                attn[(srow * 2 + b) * 1024 + h * 64 + nt * 16 + fr] =
                    (f16)(o[qb][nt][i] * invi);
        }
    }
}

// ---------------- Out GEMM: out[4096x1024] = A[4096x1024] * Wout^T + bias ----------------
// Same 3-deep pipelined structure as gemm_qkv (BK=32, ring of 3, counted vmcnt).
__global__ __launch_bounds__(256) void gemm_out(
    const f16* __restrict__ A, const f16* __restrict__ B,
    const float* __restrict__ bias, float* __restrict__ out)
{
    __shared__ f16 As[3][128 * 32];
    __shared__ f16 Bs[3][64 * 32];
    const int tid = threadIdx.x;
    const int lane = tid & 63;
    const int wave = tid >> 6;
    const int wm = wave >> 1, wn = wave & 1;
    const int bm = blockIdx.y * 128, bn = blockIdx.x * 64;
    const int fr = lane & 15, fq = lane >> 4;

    const int srow = tid >> 2;                                    // 0..63
    const int su = (tid & 3) ^ (srow & 3) ^ ((srow >> 2) & 3);
    const int uoff = (fq ^ (fr & 3) ^ ((fr >> 2) & 3)) * 8;

    f32x4 acc[4][2] = {};

    auto stg = [&](int tt, int buf) {
        const int k0 = tt * 32;
        gload_lds16(&A[(bm + srow) * 1024 + k0 + su * 8],      &As[buf][tid * 8]);
        gload_lds16(&A[(bm + 64 + srow) * 1024 + k0 + su * 8], &As[buf][2048 + tid * 8]);
        gload_lds16(&B[(bn + srow) * 1024 + k0 + su * 8],      &Bs[buf][tid * 8]);
    };

    auto step = [&](int t, int buf) {
        const int b2 = (buf + 2 >= 3) ? (buf - 1) : (buf + 2);
        if (t < 30) stg(t + 2, b2);
        f16x8 af[4], bf[2];
#pragma unroll
        for (int mt = 0; mt < 4; ++mt)
            af[mt] = *(const f16x8*)&As[buf][(wm * 64 + mt * 16 + fr) * 32 + uoff];
#pragma unroll
        for (int nt = 0; nt < 2; ++nt)
            bf[nt] = *(const f16x8*)&Bs[buf][(wn * 32 + nt * 16 + fr) * 32 + uoff];
        __builtin_amdgcn_s_setprio(1);
#pragma unroll
        for (int mt = 0; mt < 4; ++mt)
#pragma unroll
            for (int nt = 0; nt < 2; ++nt)
                acc[mt][nt] = MFMA16(af[mt], bf[nt], acc[mt][nt]);
        __builtin_amdgcn_s_setprio(0);
        if (t < 30) { asm volatile("s_waitcnt vmcnt(3)" ::: "memory"); }
        else        { asm volatile("s_waitcnt vmcnt(0)" ::: "memory"); }
        __builtin_amdgcn_s_barrier();
        __builtin_amdgcn_sched_barrier(0);
    };

    stg(0, 0);
    stg(1, 1);
    asm volatile("s_waitcnt vmcnt(3)" ::: "memory");
    __builtin_amdgcn_s_barrier();
    __builtin_amdgcn_sched_barrier(0);
#pragma unroll 1
    for (int tb = 0; tb < 30; tb += 3) {
        step(tb, 0);
        step(tb + 1, 1);
        step(tb + 2, 2);
    }
    step(30, 0);
    step(31, 1);

#pragma unroll
    for (int mt = 0; mt < 4; ++mt)
#pragma unroll
        for (int nt = 0; nt < 2; ++nt)
#pragma unroll
            for (int i = 0; i < 4; ++i) {
                int row = bm + wm * 64 + mt * 16 + fq * 4 + i;
                int col = bn + wn * 32 + nt * 16 + fr;
                out[row * 1024 + col] = acc[mt][nt][i] + bias[col];
            }
}

extern "C" void kernel_launch(void* const* d_in, const int* in_sizes, int n_in,
                              void* d_out, int out_size, void* d_ws, size_t ws_size,
                              hipStream_t stream)
{
    const float* x     = (const float*)d_in[0];
    const float* w_qkv = (const float*)d_in[1];
    const float* w_out = (const float*)d_in[2];
    const float* b_out = (const float*)d_in[3];
    float* out = (float*)d_out;

    char* ws = (char*)d_ws;
    f16* xh  = (f16*)(ws);
    f16* wqh = (f16*)(ws + 8388608);
    f16* woh = (f16*)(ws + 14680064);
    f16* qh  = (f16*)(ws + 16777216);
    f16* kh  = (f16*)(ws + 25165824);
    f16* vt  = (f16*)(ws + 33554432);
    f16* ah  = (f16*)(ws + 41943040);

    cast_all<<<8192, 256, 0, stream>>>(x, w_qkv, w_out, xh);
    gemm_qkv<<<dim3(24, 32), 256, 0, stream>>>(xh, wqh, qh, kh, vt);
    attn_kernel<<<dim3(16, 32), 256, 0, stream>>>(qh, kh, vt, ah);
    gemm_out<<<dim3(16, 32), 256, 0, stream>>>(ah, woh, b_out, out);
}

// Round 4
// 177.919 us; speedup vs baseline: 1.0234x; 1.0234x over previous
//
#include <hip/hip_runtime.h>
#include <cstdint>

typedef _Float16 f16;
typedef _Float16 f16x2 __attribute__((ext_vector_type(2)));
typedef _Float16 f16x4 __attribute__((ext_vector_type(4)));
typedef _Float16 f16x8 __attribute__((ext_vector_type(8)));
typedef float f32x4 __attribute__((ext_vector_type(4)));

#define MFMA16(a, b, c) __builtin_amdgcn_mfma_f32_16x16x32_f16(a, b, c, 0, 0, 0)
#define QSCALE 0.1803368801111243f  /* 0.125 * log2(e): scores land in log2 domain */

// direct global->LDS 16B async copy (m97 pattern)
__device__ __forceinline__ void gload_lds16(const void* g, void* l) {
    __builtin_amdgcn_global_load_lds((__attribute__((address_space(1))) void*)(g),
                                     (__attribute__((address_space(3))) void*)(l),
                                     16, 0, 0);
}

// Problem constants: S=2048, B=2, D=1024, H=16, DK=64
// ws layout (bytes):
//  xh   @ 0         : 4096x1024 f16 = 8 MB       (dead after gemm_qkv)
//  wqh  @ 8388608   : 3072x1024 f16 = 6 MB
//  woh  @ 14680064  : 1024x1024 f16 = 2 MB
//  qh   @ 16777216  : [32][2048][64] f16 = 8 MB  (PRE-SCALED by 0.125*log2e)
//  kh   @ 25165824  : [32][2048][64] f16 = 8 MB
//  vt   @ 33554432  : [32][64][2048] f16 = 8 MB  (V transposed, written by gemm_qkv)
//  ah   @ 41943040  : [4096][1024] f16 = 8 MB

// Single fused cast: outputs are contiguous in ws (xh | wqh | woh).
__global__ void cast_all(const float* __restrict__ x, const float* __restrict__ wqv,
                         const float* __restrict__ wo, f16* __restrict__ out) {
    int i = blockIdx.x * blockDim.x + threadIdx.x;  // 0..2097151 float4s
    const float* src; int li;
    if (i < 1048576)      { src = x;   li = i; }
    else if (i < 1835008) { src = wqv; li = i - 1048576; }
    else                  { src = wo;  li = i - 1835008; }
    float4 v = reinterpret_cast<const float4*>(src)[li];
    f16x4 o = {(f16)v.x, (f16)v.y, (f16)v.z, (f16)v.w};
    reinterpret_cast<f16x4*>(out)[i] = o;
}

// ---------------- QKV GEMM: C[4096x3072] = X[4096x1024] * Wqkv^T ----------------
// R7: 3-deep pipelined K-loop. BK=32, 3 LDS buffers (ring t%3): while computing
// tile t, tile t+2 is being staged; tile t+1 is landing. One raw s_barrier per
// tile with counted s_waitcnt vmcnt(4) (never drains the queue in steady state).
__global__ __launch_bounds__(256, 3) void gemm_qkv(
    const f16* __restrict__ A, const f16* __restrict__ B,
    f16* __restrict__ outq, f16* __restrict__ outk, f16* __restrict__ outvt)
{
    __shared__ f16 As[3][128 * 32];
    __shared__ f16 Bs[3][128 * 32];
    const int tid = threadIdx.x;
    const int lane = tid & 63;
    const int wave = tid >> 6;
    const int wm = wave >> 1, wn = wave & 1;
    const int bm = blockIdx.y * 128, bn = blockIdx.x * 128;
    const int fr = lane & 15, fq = lane >> 4;

    const int srow = tid >> 2;                                    // 0..63
    const int su = (tid & 3) ^ (srow & 3) ^ ((srow >> 2) & 3);    // swizzled src 16B-unit
    const int uoff = (fq ^ (fr & 3) ^ ((fr >> 2) & 3)) * 8;       // lane-const read offset

    f32x4 acc[4][4] = {};

    auto stg = [&](int tt, int buf) {
        const int k0 = tt * 32;
        gload_lds16(&A[(bm + srow) * 1024 + k0 + su * 8],      &As[buf][tid * 8]);
        gload_lds16(&A[(bm + 64 + srow) * 1024 + k0 + su * 8], &As[buf][2048 + tid * 8]);
        gload_lds16(&B[(bn + srow) * 1024 + k0 + su * 8],      &Bs[buf][tid * 8]);
        gload_lds16(&B[(bn + 64 + srow) * 1024 + k0 + su * 8], &Bs[buf][2048 + tid * 8]);
    };

    auto step = [&](int t, int buf) {
        const int b2 = (buf + 2 >= 3) ? (buf - 1) : (buf + 2);
        if (t < 30) stg(t + 2, b2);
        f16x8 af[4], bf[4];
#pragma unroll
        for (int mt = 0; mt < 4; ++mt)
            af[mt] = *(const f16x8*)&As[buf][(wm * 64 + mt * 16 + fr) * 32 + uoff];
#pragma unroll
        for (int nt = 0; nt < 4; ++nt)
            bf[nt] = *(const f16x8*)&Bs[buf][(wn * 64 + nt * 16 + fr) * 32 + uoff];
        __builtin_amdgcn_s_setprio(1);
#pragma unroll
        for (int mt = 0; mt < 4; ++mt)
#pragma unroll
            for (int nt = 0; nt < 4; ++nt)
                acc[mt][nt] = MFMA16(af[mt], bf[nt], acc[mt][nt]);
        __builtin_amdgcn_s_setprio(0);
        if (t < 30) { asm volatile("s_waitcnt vmcnt(4)" ::: "memory"); }
        else        { asm volatile("s_waitcnt vmcnt(0)" ::: "memory"); }
        __builtin_amdgcn_s_barrier();
        __builtin_amdgcn_sched_barrier(0);
    };

    stg(0, 0);
    stg(1, 1);
    asm volatile("s_waitcnt vmcnt(4)" ::: "memory");
    __builtin_amdgcn_s_barrier();
    __builtin_amdgcn_sched_barrier(0);
#pragma unroll 1
    for (int tb = 0; tb < 30; tb += 3) {
        step(tb, 0);
        step(tb + 1, 1);
        step(tb + 2, 2);
    }
    step(30, 0);
    step(31, 1);

    const int x = blockIdx.x;
    if (x < 16) {
        // Q (x<8) or K block: uniform target, row-layout [bh][s][64]
        f16* base = (x < 8) ? outq : outk;
        const float scale = (x < 8) ? QSCALE : 1.0f;
        const int coloff = (x < 8) ? bn : (bn - 1024);
#pragma unroll
        for (int mt = 0; mt < 4; ++mt)
#pragma unroll
            for (int nt = 0; nt < 4; ++nt)
#pragma unroll
                for (int i = 0; i < 4; ++i) {
                    int row = bm + wm * 64 + mt * 16 + fq * 4 + i;  // (s*2+b)
                    int col = coloff + wn * 64 + nt * 16 + fr;      // 0..1023
                    int s = row >> 1, b = row & 1;
                    int h = col >> 6, dk = col & 63;
                    base[((b * 16 + h) * 2048 + s) * 64 + dk] = (f16)(acc[mt][nt][i] * scale);
                }
    } else {
        // V block: LDS transpose (2 passes over wn halves) -> vt[bh][dk][s]
        const int xb = x - 16;              // 0..7
        const int s0 = bm >> 1;             // 64-aligned s base
        f16* Ts = &As[0][0];                // [128][76] = 9728 f16 (fits in As[3][4096])
#pragma unroll
        for (int p = 0; p < 2; ++p) {
            __syncthreads();
            if (wn == p) {
#pragma unroll
                for (int mt = 0; mt < 4; ++mt)
#pragma unroll
                    for (int nt = 0; nt < 4; ++nt)
#pragma unroll
                        for (int i = 0; i < 4; ++i) {
                            int row = wm * 64 + mt * 16 + fq * 4 + i;  // 0..127 local
                            int cl = nt * 16 + fr;                     // 0..63 local col
                            Ts[(cl * 2 + (row & 1)) * 76 + (row >> 1)] = (f16)acc[mt][nt][i];
                        }
            }
            __syncthreads();
            const int h = xb * 2 + p;
            const int sj = tid & 7;
#pragma unroll
            for (int it = 0; it < 4; ++it) {
                int idx = (tid >> 3) + it * 32;     // 0..127
                int bsel = idx & 1, dk = idx >> 1;  // b, dk(=cl)
                f16x8 v = *(const f16x8*)&Ts[(dk * 2 + bsel) * 76 + sj * 8];
                *(f16x8*)&outvt[((bsel * 16 + h) * 64 + dk) * 2048 + s0 + sj * 8] = v;
            }
        }
    }
}

// ---------------- Flash attention (causal) — R9: 8-wave TLP + in-register P ----------------
// Back to the R6 8-wave/16-row structure (best measured), plus:
//  (1) swapped QK^T (mfma(K,Q) -> P^T[k][q], verified in R8) with P redistributed to
//      the PV A-frag layout IN REGISTERS: movement is along the fq lane-axis only
//      (src lane = fr + 32*(fq&1) (+16)); 16 __shfl + 8 selects replace the whole
//      P LDS round-trip (16 ds_write + lgkm drain + 2 ds_read) and delete plds.
//  (2) 3-buffer K/V ring with counted s_waitcnt vmcnt(2) + raw s_barrier (R7 gemm
//      pattern): prefetched loads stay in flight across barriers, no full drain.
//  (3) __launch_bounds__(512,6): 3 blocks/CU = 24 waves/CU (LDS 49152 B).
__global__ __launch_bounds__(512, 6) void attn_kernel(
    const f16* __restrict__ qg, const f16* __restrict__ kg,
    const f16* __restrict__ vtg, f16* __restrict__ attn)
{
    __shared__ f16 Ks[3][64 * 64];
    __shared__ f16 Vs[3][64 * 64];
    const int tid = threadIdx.x;
    const int lane = tid & 63;
    const int wave = tid >> 6;      // 0..7
    const int qpair = blockIdx.x;   // 0..15 (qpair=0 has longest stream, dispatched first)
    const int bh = blockIdx.y;
    const int b = bh >> 4, h = bh & 15;
    const int fr = lane & 15, fq = lane >> 4;

    const bool isB = wave < 4;
    const int w4 = wave & 3;
    const int qrow = (isB ? (31 - qpair) : qpair) * 64 + w4 * 16;  // wave's 16-row base
    const int nB = 32 - qpair;              // chunks staged by the block (>= 17)
    const int nK = (qrow >> 6) + 1;         // chunks this wave computes (B-waves: == nB)

    const f16* Q  = qg  + bh * 2048 * 64;
    const f16* K  = kg  + bh * 2048 * 64;
    const f16* VT = vtg + bh * 64 * 2048;

    const int sr = tid >> 3;                // 0..63: full 64-row chunk in one issue
    const int scu = (tid & 7) ^ (sr & 7);

    // Q fragments (B-operand of swapped QK^T): lane holds Q[q=fr][dk=fq*8..]
    f16x8 aq0 = *(const f16x8*)&Q[(qrow + fr) * 64 + fq * 8];
    f16x8 aq1 = *(const f16x8*)&Q[(qrow + fr) * 64 + 32 + fq * 8];

    f32x4 o[4] = {};
    float lsum = 0.f;

    // lane-permute constants for in-register P redistribution (along fq axis only)
    const int la = fr + ((fq & 1) << 5);    // src lane A
    const int lb = la + 16;                 // src lane B
    const bool hi = (fq & 2) != 0;          // ct-select: fq in {2,3} -> odd ct

    auto stage = [&](int kc, f16* Ksb, f16* Vsb) {
        const int kb = kc * 64;
        gload_lds16(&K[(kb + sr) * 64 + scu * 8], &Ksb[tid * 8]);
        gload_lds16(&VT[sr * 2048 + kb + scu * 8], &Vsb[tid * 8]);
    };

    auto compute = [&](int kb, const f16* Ksb, const f16* Vsb, bool domask) {
        f32x4 sc[4] = {};
        // swapped QK^T: D[k_local = ct*16 + fq*4 + i][q = fr]
        __builtin_amdgcn_s_setprio(1);
#pragma unroll
        for (int ct = 0; ct < 4; ++ct) {
            int r = ct * 16 + fr;
            f16x8 kf0 = *(const f16x8*)&Ksb[r * 64 + ((fq ^ (r & 7)) * 8)];
            f16x8 kf1 = *(const f16x8*)&Ksb[r * 64 + (((4 + fq) ^ (r & 7)) * 8)];
            sc[ct] = MFMA16(kf0, aq0, sc[ct]);
            sc[ct] = MFMA16(kf1, aq1, sc[ct]);
        }
        __builtin_amdgcn_s_setprio(0);
        if (domask) {
#pragma unroll
            for (int ct = 0; ct < 4; ++ct) {
                int kk = kb + ct * 16 + fq * 4;   // k index of element i is kk+i
#pragma unroll
                for (int i = 0; i < 4; ++i)
                    if (kk + i > qrow + fr) sc[ct][i] = -1e30f;
            }
        }
        // exp2 + pack: P2[ct][w] = (p[k=16ct+4fq+2w], p[+1]) packed f16x2, q = fr
        unsigned P2[4][2];
#pragma unroll
        for (int ct = 0; ct < 4; ++ct) {
            float p0 = __builtin_amdgcn_exp2f(sc[ct][0]);
            float p1 = __builtin_amdgcn_exp2f(sc[ct][1]);
            float p2 = __builtin_amdgcn_exp2f(sc[ct][2]);
            float p3 = __builtin_amdgcn_exp2f(sc[ct][3]);
            lsum += (p0 + p1) + (p2 + p3);
            f16x2 e0 = {(f16)p0, (f16)p1};
            f16x2 e1 = {(f16)p2, (f16)p3};
            P2[ct][0] = __builtin_bit_cast(unsigned, e0);
            P2[ct][1] = __builtin_bit_cast(unsigned, e1);
        }
        // Redistribute to PV A-frag: lane (fr,fq) needs p[q=fr][k = ks*32 + 8fq + e].
        // Sources: lanes la/lb (same fr, fq_s = 2(fq&1)(+1)); ct = (ks? 2:0) + (fq>>1).
        unsigned a0 = __shfl((int)P2[0][0], la), b0 = __shfl((int)P2[1][0], la);
        unsigned a1 = __shfl((int)P2[0][1], la), b1 = __shfl((int)P2[1][1], la);
        unsigned a2 = __shfl((int)P2[0][0], lb), b2 = __shfl((int)P2[1][0], lb);
        unsigned a3 = __shfl((int)P2[0][1], lb), b3 = __shfl((int)P2[1][1], lb);
        uint4 W0 = {hi ? b0 : a0, hi ? b1 : a1, hi ? b2 : a2, hi ? b3 : a3};
        f16x8 apk0 = __builtin_bit_cast(f16x8, W0);
        unsigned c0 = __shfl((int)P2[2][0], la), d0 = __shfl((int)P2[3][0], la);
        unsigned c1 = __shfl((int)P2[2][1], la), d1 = __shfl((int)P2[3][1], la);
        unsigned c2 = __shfl((int)P2[2][0], lb), d2 = __shfl((int)P2[3][0], lb);
        unsigned c3 = __shfl((int)P2[2][1], lb), d3 = __shfl((int)P2[3][1], lb);
        uint4 W1 = {hi ? d0 : c0, hi ? d1 : c1, hi ? d2 : c2, hi ? d3 : c3};
        f16x8 apk1 = __builtin_bit_cast(f16x8, W1);
        // PV: O[q][dk] += P·V ; B-frag = V^T rows (dk), same as verified R6/R8 path
        __builtin_amdgcn_s_setprio(1);
#pragma unroll
        for (int nt = 0; nt < 4; ++nt) {
            int dk = nt * 16 + fr;
            f16x8 bv0 = *(const f16x8*)&Vsb[dk * 64 + ((fq ^ (dk & 7)) * 8)];
            f16x8 bv1 = *(const f16x8*)&Vsb[dk * 64 + (((4 + fq) ^ (dk & 7)) * 8)];
            o[nt] = MFMA16(apk0, bv0, o[nt]);
            o[nt] = MFMA16(apk1, bv1, o[nt]);
        }
        __builtin_amdgcn_s_setprio(0);
    };

    // prologue: stage chunks 0,1; wait chunk 0 landed (chunk 1 may stay in flight)
    stage(0, Ks[0], Vs[0]);
    stage(1, Ks[1], Vs[1]);
    asm volatile("s_waitcnt vmcnt(2)" ::: "memory");
    __builtin_amdgcn_s_barrier();
    __builtin_amdgcn_sched_barrier(0);

    int cur = 0;
#pragma unroll 1
    for (int kc = 0; kc < nB; ++kc) {
        if (kc + 2 < nB) {
            int b2 = cur + 2; if (b2 >= 3) b2 -= 3;
            stage(kc + 2, Ks[b2], Vs[b2]);
        }
        if (kc < nK) compute(kc * 64, Ks[cur], Vs[cur], kc * 64 + 63 > qrow);
        if (kc + 2 < nB) { asm volatile("s_waitcnt vmcnt(2)" ::: "memory"); }
        else             { asm volatile("s_waitcnt vmcnt(0)" ::: "memory"); }
        __builtin_amdgcn_s_barrier();
        __builtin_amdgcn_sched_barrier(0);
        if (++cur == 3) cur = 0;
    }

    // epilogue: lsum at lane (fr,fq) is the partial row-sum for q=fr over its k-subset
    float rs = lsum;
    rs += __shfl_xor(rs, 16);
    rs += __shfl_xor(rs, 32);
    float inv = __builtin_amdgcn_rcpf(rs);
#pragma unroll
    for (int i = 0; i < 4; ++i) {
        float invi = __shfl(inv, fq * 4 + i);   // inv for q-local = fq*4+i (lane fr'=q)
        int srow = qrow + fq * 4 + i;
#pragma unroll
        for (int nt = 0; nt < 4; ++nt)
            attn[(srow * 2 + b) * 1024 + h * 64 + nt * 16 + fr] = (f16)(o[nt][i] * invi);
    }
}

// ---------------- Out GEMM: out[4096x1024] = A[4096x1024] * Wout^T + bias ----------------
// Same 3-deep pipelined structure as gemm_qkv (BK=32, ring of 3, counted vmcnt).
__global__ __launch_bounds__(256) void gemm_out(
    const f16* __restrict__ A, const f16* __restrict__ B,
    const float* __restrict__ bias, float* __restrict__ out)
{
    __shared__ f16 As[3][128 * 32];
    __shared__ f16 Bs[3][64 * 32];
    const int tid = threadIdx.x;
    const int lane = tid & 63;
    const int wave = tid >> 6;
    const int wm = wave >> 1, wn = wave & 1;
    const int bm = blockIdx.y * 128, bn = blockIdx.x * 64;
    const int fr = lane & 15, fq = lane >> 4;

    const int srow = tid >> 2;                                    // 0..63
    const int su = (tid & 3) ^ (srow & 3) ^ ((srow >> 2) & 3);
    const int uoff = (fq ^ (fr & 3) ^ ((fr >> 2) & 3)) * 8;

    f32x4 acc[4][2] = {};

    auto stg = [&](int tt, int buf) {
        const int k0 = tt * 32;
        gload_lds16(&A[(bm + srow) * 1024 + k0 + su * 8],      &As[buf][tid * 8]);
        gload_lds16(&A[(bm + 64 + srow) * 1024 + k0 + su * 8], &As[buf][2048 + tid * 8]);
        gload_lds16(&B[(bn + srow) * 1024 + k0 + su * 8],      &Bs[buf][tid * 8]);
    };

    auto step = [&](int t, int buf) {
        const int b2 = (buf + 2 >= 3) ? (buf - 1) : (buf + 2);
        if (t < 30) stg(t + 2, b2);
        f16x8 af[4], bf[2];
#pragma unroll
        for (int mt = 0; mt < 4; ++mt)
            af[mt] = *(const f16x8*)&As[buf][(wm * 64 + mt * 16 + fr) * 32 + uoff];
#pragma unroll
        for (int nt = 0; nt < 2; ++nt)
            bf[nt] = *(const f16x8*)&Bs[buf][(wn * 32 + nt * 16 + fr) * 32 + uoff];
        __builtin_amdgcn_s_setprio(1);
#pragma unroll
        for (int mt = 0; mt < 4; ++mt)
#pragma unroll
            for (int nt = 0; nt < 2; ++nt)
                acc[mt][nt] = MFMA16(af[mt], bf[nt], acc[mt][nt]);
        __builtin_amdgcn_s_setprio(0);
        if (t < 30) { asm volatile("s_waitcnt vmcnt(3)" ::: "memory"); }
        else        { asm volatile("s_waitcnt vmcnt(0)" ::: "memory"); }
        __builtin_amdgcn_s_barrier();
        __builtin_amdgcn_sched_barrier(0);
    };

    stg(0, 0);
    stg(1, 1);
    asm volatile("s_waitcnt vmcnt(3)" ::: "memory");
    __builtin_amdgcn_s_barrier();
    __builtin_amdgcn_sched_barrier(0);
#pragma unroll 1
    for (int tb = 0; tb < 30; tb += 3) {
        step(tb, 0);
        step(tb + 1, 1);
        step(tb + 2, 2);
    }
    step(30, 0);
    step(31, 1);

#pragma unroll
    for (int mt = 0; mt < 4; ++mt)
#pragma unroll
        for (int nt = 0; nt < 2; ++nt)
#pragma unroll
            for (int i = 0; i < 4; ++i) {
                int row = bm + wm * 64 + mt * 16 + fq * 4 + i;
                int col = bn + wn * 32 + nt * 16 + fr;
                out[row * 1024 + col] = acc[mt][nt][i] + bias[col];
            }
}

extern "C" void kernel_launch(void* const* d_in, const int* in_sizes, int n_in,
                              void* d_out, int out_size, void* d_ws, size_t ws_size,
                              hipStream_t stream)
{
    const float* x     = (const float*)d_in[0];
    const float* w_qkv = (const float*)d_in[1];
    const float* w_out = (const float*)d_in[2];
    const float* b_out = (const float*)d_in[3];
    float* out = (float*)d_out;

    char* ws = (char*)d_ws;
    f16* xh  = (f16*)(ws);
    f16* wqh = (f16*)(ws + 8388608);
    f16* woh = (f16*)(ws + 14680064);
    f16* qh  = (f16*)(ws + 16777216);
    f16* kh  = (f16*)(ws + 25165824);
    f16* vt  = (f16*)(ws + 33554432);
    f16* ah  = (f16*)(ws + 41943040);

    cast_all<<<8192, 256, 0, stream>>>(x, w_qkv, w_out, xh);
    gemm_qkv<<<dim3(24, 32), 256, 0, stream>>>(xh, wqh, qh, kh, vt);
    attn_kernel<<<dim3(16, 32), 512, 0, stream>>>(qh, kh, vt, ah);
    gemm_out<<<dim3(16, 32), 256, 0, stream>>>(ah, woh, b_out, out);
}

// Round 5
// 175.034 us; speedup vs baseline: 1.0403x; 1.0165x over previous
//
#include <hip/hip_runtime.h>
#include <cstdint>

typedef _Float16 f16;
typedef _Float16 f16x4 __attribute__((ext_vector_type(4)));
typedef _Float16 f16x8 __attribute__((ext_vector_type(8)));
typedef float f32x4 __attribute__((ext_vector_type(4)));

#define MFMA16(a, b, c) __builtin_amdgcn_mfma_f32_16x16x32_f16(a, b, c, 0, 0, 0)
#define QSCALE 0.1803368801111243f  /* 0.125 * log2(e): scores land in log2 domain */

// direct global->LDS 16B async copy (m97 pattern)
__device__ __forceinline__ void gload_lds16(const void* g, void* l) {
    __builtin_amdgcn_global_load_lds((__attribute__((address_space(1))) void*)(g),
                                     (__attribute__((address_space(3))) void*)(l),
                                     16, 0, 0);
}

// Problem constants: S=2048, B=2, D=1024, H=16, DK=64
// ws layout (bytes):
//  xh   @ 0         : 4096x1024 f16 = 8 MB       (dead after gemm_qkv)
//  wqh  @ 8388608   : 3072x1024 f16 = 6 MB
//  woh  @ 14680064  : 1024x1024 f16 = 2 MB
//  qh   @ 16777216  : [32][2048][64] f16 = 8 MB  (PRE-SCALED by 0.125*log2e)
//  kh   @ 25165824  : [32][2048][64] f16 = 8 MB
//  vt   @ 33554432  : [32][64][2048] f16 = 8 MB  (V transposed, written by gemm_qkv)
//  ah   @ 41943040  : [4096][1024] f16 = 8 MB

// Single fused cast: outputs are contiguous in ws (xh | wqh | woh).
__global__ void cast_all(const float* __restrict__ x, const float* __restrict__ wqv,
                         const float* __restrict__ wo, f16* __restrict__ out) {
    int i = blockIdx.x * blockDim.x + threadIdx.x;  // 0..2097151 float4s
    const float* src; int li;
    if (i < 1048576)      { src = x;   li = i; }
    else if (i < 1835008) { src = wqv; li = i - 1048576; }
    else                  { src = wo;  li = i - 1835008; }
    float4 v = reinterpret_cast<const float4*>(src)[li];
    f16x4 o = {(f16)v.x, (f16)v.y, (f16)v.z, (f16)v.w};
    reinterpret_cast<f16x4*>(out)[i] = o;
}

// ---------------- QKV GEMM: C[4096x3072] = X[4096x1024] * Wqkv^T ----------------
// R7: 3-deep pipelined K-loop. BK=32, 3 LDS buffers (ring t%3): while computing
// tile t, tile t+2 is being staged; tile t+1 is landing. One raw s_barrier per
// tile with counted s_waitcnt vmcnt(4) (never drains the queue in steady state).
__global__ __launch_bounds__(256, 3) void gemm_qkv(
    const f16* __restrict__ A, const f16* __restrict__ B,
    f16* __restrict__ outq, f16* __restrict__ outk, f16* __restrict__ outvt)
{
    __shared__ f16 As[3][128 * 32];
    __shared__ f16 Bs[3][128 * 32];
    const int tid = threadIdx.x;
    const int lane = tid & 63;
    const int wave = tid >> 6;
    const int wm = wave >> 1, wn = wave & 1;
    const int bm = blockIdx.y * 128, bn = blockIdx.x * 128;
    const int fr = lane & 15, fq = lane >> 4;

    const int srow = tid >> 2;                                    // 0..63
    const int su = (tid & 3) ^ (srow & 3) ^ ((srow >> 2) & 3);    // swizzled src 16B-unit
    const int uoff = (fq ^ (fr & 3) ^ ((fr >> 2) & 3)) * 8;       // lane-const read offset

    f32x4 acc[4][4] = {};

    auto stg = [&](int tt, int buf) {
        const int k0 = tt * 32;
        gload_lds16(&A[(bm + srow) * 1024 + k0 + su * 8],      &As[buf][tid * 8]);
        gload_lds16(&A[(bm + 64 + srow) * 1024 + k0 + su * 8], &As[buf][2048 + tid * 8]);
        gload_lds16(&B[(bn + srow) * 1024 + k0 + su * 8],      &Bs[buf][tid * 8]);
        gload_lds16(&B[(bn + 64 + srow) * 1024 + k0 + su * 8], &Bs[buf][2048 + tid * 8]);
    };

    auto step = [&](int t, int buf) {
        const int b2 = (buf + 2 >= 3) ? (buf - 1) : (buf + 2);
        if (t < 30) stg(t + 2, b2);
        f16x8 af[4], bf[4];
#pragma unroll
        for (int mt = 0; mt < 4; ++mt)
            af[mt] = *(const f16x8*)&As[buf][(wm * 64 + mt * 16 + fr) * 32 + uoff];
#pragma unroll
        for (int nt = 0; nt < 4; ++nt)
            bf[nt] = *(const f16x8*)&Bs[buf][(wn * 64 + nt * 16 + fr) * 32 + uoff];
        __builtin_amdgcn_s_setprio(1);
#pragma unroll
        for (int mt = 0; mt < 4; ++mt)
#pragma unroll
            for (int nt = 0; nt < 4; ++nt)
                acc[mt][nt] = MFMA16(af[mt], bf[nt], acc[mt][nt]);
        __builtin_amdgcn_s_setprio(0);
        if (t < 30) { asm volatile("s_waitcnt vmcnt(4)" ::: "memory"); }
        else        { asm volatile("s_waitcnt vmcnt(0)" ::: "memory"); }
        __builtin_amdgcn_s_barrier();
        __builtin_amdgcn_sched_barrier(0);
    };

    stg(0, 0);
    stg(1, 1);
    asm volatile("s_waitcnt vmcnt(4)" ::: "memory");
    __builtin_amdgcn_s_barrier();
    __builtin_amdgcn_sched_barrier(0);
#pragma unroll 1
    for (int tb = 0; tb < 30; tb += 3) {
        step(tb, 0);
        step(tb + 1, 1);
        step(tb + 2, 2);
    }
    step(30, 0);
    step(31, 1);

    const int x = blockIdx.x;
    if (x < 16) {
        // Q (x<8) or K block: uniform target, row-layout [bh][s][64]
        f16* base = (x < 8) ? outq : outk;
        const float scale = (x < 8) ? QSCALE : 1.0f;
        const int coloff = (x < 8) ? bn : (bn - 1024);
#pragma unroll
        for (int mt = 0; mt < 4; ++mt)
#pragma unroll
            for (int nt = 0; nt < 4; ++nt)
#pragma unroll
                for (int i = 0; i < 4; ++i) {
                    int row = bm + wm * 64 + mt * 16 + fq * 4 + i;  // (s*2+b)
                    int col = coloff + wn * 64 + nt * 16 + fr;      // 0..1023
                    int s = row >> 1, b = row & 1;
                    int h = col >> 6, dk = col & 63;
                    base[((b * 16 + h) * 2048 + s) * 64 + dk] = (f16)(acc[mt][nt][i] * scale);
                }
    } else {
        // V block: LDS transpose (2 passes over wn halves) -> vt[bh][dk][s]
        const int xb = x - 16;              // 0..7
        const int s0 = bm >> 1;             // 64-aligned s base
        f16* Ts = &As[0][0];                // [128][76] = 9728 f16 (fits in As[3][4096])
#pragma unroll
        for (int p = 0; p < 2; ++p) {
            __syncthreads();
            if (wn == p) {
#pragma unroll
                for (int mt = 0; mt < 4; ++mt)
#pragma unroll
                    for (int nt = 0; nt < 4; ++nt)
#pragma unroll
                        for (int i = 0; i < 4; ++i) {
                            int row = wm * 64 + mt * 16 + fq * 4 + i;  // 0..127 local
                            int cl = nt * 16 + fr;                     // 0..63 local col
                            Ts[(cl * 2 + (row & 1)) * 76 + (row >> 1)] = (f16)acc[mt][nt][i];
                        }
            }
            __syncthreads();
            const int h = xb * 2 + p;
            const int sj = tid & 7;
#pragma unroll
            for (int it = 0; it < 4; ++it) {
                int idx = (tid >> 3) + it * 32;     // 0..127
                int bsel = idx & 1, dk = idx >> 1;  // b, dk(=cl)
                f16x8 v = *(const f16x8*)&Ts[(dk * 2 + bsel) * 76 + sj * 8];
                *(f16x8*)&outvt[((bsel * 16 + h) * 64 + dk) * 2048 + s0 + sj * 8] = v;
            }
        }
    }
}

// ---------------- Flash attention (causal, no-max softmax) — R10: R6 + XCD swizzle ----------
// Exact R6 compute (best measured: 44.5us): 8 waves (512 thr), waves 0-3 = tile
// B(31-qpair), waves 4-7 = tile A(qpair), LDS-P round-trip, double-buffered K/V.
// NEW: bijective XCD-aware block remap. HW linear id w = bx + 16*by, XCD = w%8.
// Old mapping sprayed one bh's 16 blocks over all 8 XCDs (each XCD touched 32 bh
// = 16MB K/V -> L2 thrash, FETCH 62.5MB vs 24MB ideal). New: bh%8 == XCD, so each
// XCD serves 4 bh x 512KB = 2MB K/V from its own L2; qpair=0 (longest) first.
__global__ __launch_bounds__(512) void attn_kernel(
    const f16* __restrict__ qg, const f16* __restrict__ kg,
    const f16* __restrict__ vtg, f16* __restrict__ attn)
{
    __shared__ f16 Ks[2][64 * 64];
    __shared__ f16 Vs[2][64 * 64];
    __shared__ f16 plds[8][16 * 72];
    const int tid = threadIdx.x;
    const int lane = tid & 63;
    const int wave = tid >> 6;      // 0..7

    // XCD-aware remap (bijective on 512): XCD = w&7 == bh&7
    const int w = blockIdx.x + (blockIdx.y << 4);
    const int xcd = w & 7;
    const int idx = w >> 3;                  // 0..63
    const int bh = xcd + ((idx & 3) << 3);   // 0..31, bh%8 == xcd
    const int qpair = idx >> 2;              // 0..15, longest stream first

    const int b = bh >> 4, h = bh & 15;
    const int fr = lane & 15, fq = lane >> 4;

    const bool isB = wave < 4;
    const int w4 = wave & 3;
    const int qrow = (isB ? (31 - qpair) : qpair) * 64 + w4 * 16;  // wave's 16-row base
    const int nB = 32 - qpair;              // chunks streamed by the block
    const int nK = isB ? nB : (qpair + 1);  // chunks this wave computes

    const f16* Q  = qg  + bh * 2048 * 64;
    const f16* K  = kg  + bh * 2048 * 64;
    const f16* VT = vtg + bh * 64 * 2048;
    f16* P = plds[wave];

    const int sr = tid >> 3;                // 0..63: full 64-row chunk in one issue
    const int scu = (tid & 7) ^ (sr & 7);

    f16x8 aq0 = *(const f16x8*)&Q[(qrow + fr) * 64 + fq * 8];
    f16x8 aq1 = *(const f16x8*)&Q[(qrow + fr) * 64 + 32 + fq * 8];

    f32x4 o[4] = {};
    float l[4] = {};

    auto stage = [&](int kc, int buf) {
        const int kb = kc * 64;
        gload_lds16(&K[(kb + sr) * 64 + scu * 8], &Ks[buf][tid * 8]);
        gload_lds16(&VT[sr * 2048 + kb + scu * 8], &Vs[buf][tid * 8]);
    };

    auto compute = [&](int kb, const f16* Ksb, const f16* Vsb, bool domask) {
        f32x4 sc[4] = {};
#pragma unroll
        for (int ct = 0; ct < 4; ++ct) {
            int r = ct * 16 + fr;
            f16x8 b0 = *(const f16x8*)&Ksb[r * 64 + ((fq ^ (r & 7)) * 8)];
            f16x8 b1 = *(const f16x8*)&Ksb[r * 64 + (((4 + fq) ^ (r & 7)) * 8)];
            sc[ct] = MFMA16(aq0, b0, sc[ct]);
            sc[ct] = MFMA16(aq1, b1, sc[ct]);
        }
        if (domask) {
#pragma unroll
            for (int ct = 0; ct < 4; ++ct) {
                int kcol = kb + ct * 16 + fr;
#pragma unroll
                for (int i = 0; i < 4; ++i)
                    if (kcol > qrow + fq * 4 + i) sc[ct][i] = -1e30f;
            }
        }
#pragma unroll
        for (int i = 0; i < 4; ++i) {
            float p0 = __builtin_amdgcn_exp2f(sc[0][i]);
            float p1 = __builtin_amdgcn_exp2f(sc[1][i]);
            float p2 = __builtin_amdgcn_exp2f(sc[2][i]);
            float p3 = __builtin_amdgcn_exp2f(sc[3][i]);
            l[i] += (p0 + p1) + (p2 + p3);
            P[(fq * 4 + i) * 72 + fr]      = (f16)p0;
            P[(fq * 4 + i) * 72 + 16 + fr] = (f16)p1;
            P[(fq * 4 + i) * 72 + 32 + fr] = (f16)p2;
            P[(fq * 4 + i) * 72 + 48 + fr] = (f16)p3;
        }
        f16x8 ap0 = *(const f16x8*)&P[fr * 72 + fq * 8];
        f16x8 ap1 = *(const f16x8*)&P[fr * 72 + 32 + fq * 8];
#pragma unroll
        for (int nt = 0; nt < 4; ++nt) {
            int dk = nt * 16 + fr;
            f16x8 bv0 = *(const f16x8*)&Vsb[dk * 64 + ((fq ^ (dk & 7)) * 8)];
            f16x8 bv1 = *(const f16x8*)&Vsb[dk * 64 + (((4 + fq) ^ (dk & 7)) * 8)];
            o[nt] = MFMA16(ap0, bv0, o[nt]);
            o[nt] = MFMA16(ap1, bv1, o[nt]);
        }
    };

    stage(0, 0);
    for (int kc = 0; kc < nB; ++kc) {
        const int kb = kc * 64;
        const int cur = kc & 1;
        __syncthreads();
        if (kc + 1 < nB) stage(kc + 1, cur ^ 1);
        if (kc < nK) compute(kb, Ks[cur], Vs[cur], kb + 63 > qrow);
    }

#pragma unroll
    for (int i = 0; i < 4; ++i) {
        float rs = l[i];
        rs += __shfl_xor(rs, 1);
        rs += __shfl_xor(rs, 2);
        rs += __shfl_xor(rs, 4);
        rs += __shfl_xor(rs, 8);
        float inv = __builtin_amdgcn_rcpf(rs);
        int srow = qrow + fq * 4 + i;
#pragma unroll
        for (int nt = 0; nt < 4; ++nt)
            attn[(srow * 2 + b) * 1024 + h * 64 + nt * 16 + fr] = (f16)(o[nt][i] * inv);
    }
}

// ---------------- Out GEMM: out[4096x1024] = A[4096x1024] * Wout^T + bias ----------------
// Same 3-deep pipelined structure as gemm_qkv (BK=32, ring of 3, counted vmcnt).
__global__ __launch_bounds__(256) void gemm_out(
    const f16* __restrict__ A, const f16* __restrict__ B,
    const float* __restrict__ bias, float* __restrict__ out)
{
    __shared__ f16 As[3][128 * 32];
    __shared__ f16 Bs[3][64 * 32];
    const int tid = threadIdx.x;
    const int lane = tid & 63;
    const int wave = tid >> 6;
    const int wm = wave >> 1, wn = wave & 1;
    const int bm = blockIdx.y * 128, bn = blockIdx.x * 64;
    const int fr = lane & 15, fq = lane >> 4;

    const int srow = tid >> 2;                                    // 0..63
    const int su = (tid & 3) ^ (srow & 3) ^ ((srow >> 2) & 3);
    const int uoff = (fq ^ (fr & 3) ^ ((fr >> 2) & 3)) * 8;

    f32x4 acc[4][2] = {};

    auto stg = [&](int tt, int buf) {
        const int k0 = tt * 32;
        gload_lds16(&A[(bm + srow) * 1024 + k0 + su * 8],      &As[buf][tid * 8]);
        gload_lds16(&A[(bm + 64 + srow) * 1024 + k0 + su * 8], &As[buf][2048 + tid * 8]);
        gload_lds16(&B[(bn + srow) * 1024 + k0 + su * 8],      &Bs[buf][tid * 8]);
    };

    auto step = [&](int t, int buf) {
        const int b2 = (buf + 2 >= 3) ? (buf - 1) : (buf + 2);
        if (t < 30) stg(t + 2, b2);
        f16x8 af[4], bf[2];
#pragma unroll
        for (int mt = 0; mt < 4; ++mt)
            af[mt] = *(const f16x8*)&As[buf][(wm * 64 + mt * 16 + fr) * 32 + uoff];
#pragma unroll
        for (int nt = 0; nt < 2; ++nt)
            bf[nt] = *(const f16x8*)&Bs[buf][(wn * 32 + nt * 16 + fr) * 32 + uoff];
        __builtin_amdgcn_s_setprio(1);
#pragma unroll
        for (int mt = 0; mt < 4; ++mt)
#pragma unroll
            for (int nt = 0; nt < 2; ++nt)
                acc[mt][nt] = MFMA16(af[mt], bf[nt], acc[mt][nt]);
        __builtin_amdgcn_s_setprio(0);
        if (t < 30) { asm volatile("s_waitcnt vmcnt(3)" ::: "memory"); }
        else        { asm volatile("s_waitcnt vmcnt(0)" ::: "memory"); }
        __builtin_amdgcn_s_barrier();
        __builtin_amdgcn_sched_barrier(0);
    };

    stg(0, 0);
    stg(1, 1);
    asm volatile("s_waitcnt vmcnt(3)" ::: "memory");
    __builtin_amdgcn_s_barrier();
    __builtin_amdgcn_sched_barrier(0);
#pragma unroll 1
    for (int tb = 0; tb < 30; tb += 3) {
        step(tb, 0);
        step(tb + 1, 1);
        step(tb + 2, 2);
    }
    step(30, 0);
    step(31, 1);

#pragma unroll
    for (int mt = 0; mt < 4; ++mt)
#pragma unroll
        for (int nt = 0; nt < 2; ++nt)
#pragma unroll
            for (int i = 0; i < 4; ++i) {
                int row = bm + wm * 64 + mt * 16 + fq * 4 + i;
                int col = bn + wn * 32 + nt * 16 + fr;
                out[row * 1024 + col] = acc[mt][nt][i] + bias[col];
            }
}

extern "C" void kernel_launch(void* const* d_in, const int* in_sizes, int n_in,
                              void* d_out, int out_size, void* d_ws, size_t ws_size,
                              hipStream_t stream)
{
    const float* x     = (const float*)d_in[0];
    const float* w_qkv = (const float*)d_in[1];
    const float* w_out = (const float*)d_in[2];
    const float* b_out = (const float*)d_in[3];
    float* out = (float*)d_out;

    char* ws = (char*)d_ws;
    f16* xh  = (f16*)(ws);
    f16* wqh = (f16*)(ws + 8388608);
    f16* woh = (f16*)(ws + 14680064);
    f16* qh  = (f16*)(ws + 16777216);
    f16* kh  = (f16*)(ws + 25165824);
    f16* vt  = (f16*)(ws + 33554432);
    f16* ah  = (f16*)(ws + 41943040);

    cast_all<<<8192, 256, 0, stream>>>(x, w_qkv, w_out, xh);
    gemm_qkv<<<dim3(24, 32), 256, 0, stream>>>(xh, wqh, qh, kh, vt);
    attn_kernel<<<dim3(16, 32), 512, 0, stream>>>(qh, kh, vt, ah);
    gemm_out<<<dim3(16, 32), 256, 0, stream>>>(ah, woh, b_out, out);
}

// Round 6
// 171.914 us; speedup vs baseline: 1.0592x; 1.0182x over previous
//
#include <hip/hip_runtime.h>
#include <cstdint>

typedef _Float16 f16;
typedef _Float16 f16x4 __attribute__((ext_vector_type(4)));
typedef _Float16 f16x8 __attribute__((ext_vector_type(8)));
typedef float f32x4 __attribute__((ext_vector_type(4)));

#define MFMA16(a, b, c) __builtin_amdgcn_mfma_f32_16x16x32_f16(a, b, c, 0, 0, 0)
#define QSCALE 0.1803368801111243f  /* 0.125 * log2(e): scores land in log2 domain */

// direct global->LDS 16B async copy (m97 pattern)
__device__ __forceinline__ void gload_lds16(const void* g, void* l) {
    __builtin_amdgcn_global_load_lds((__attribute__((address_space(1))) void*)(g),
                                     (__attribute__((address_space(3))) void*)(l),
                                     16, 0, 0);
}

// Problem constants: S=2048, B=2, D=1024, H=16, DK=64
// ws layout (bytes):
//  xh   @ 0         : 4096x1024 f16 = 8 MB       (dead after gemm_qkv)
//  wqh  @ 8388608   : 3072x1024 f16 = 6 MB
//  woh  @ 14680064  : 1024x1024 f16 = 2 MB
//  qh   @ 16777216  : [32][2048][64] f16 = 8 MB  (PRE-SCALED by 0.125*log2e)
//  kh   @ 25165824  : [32][2048][64] f16 = 8 MB
//  vt   @ 33554432  : [32][64][2048] f16 = 8 MB  (V transposed, written by gemm_qkv)
//  ah   @ 41943040  : [4096][1024] f16 = 8 MB

// Single fused cast: outputs are contiguous in ws (xh | wqh | woh).
__global__ void cast_all(const float* __restrict__ x, const float* __restrict__ wqv,
                         const float* __restrict__ wo, f16* __restrict__ out) {
    int i = blockIdx.x * blockDim.x + threadIdx.x;  // 0..2097151 float4s
    const float* src; int li;
    if (i < 1048576)      { src = x;   li = i; }
    else if (i < 1835008) { src = wqv; li = i - 1048576; }
    else                  { src = wo;  li = i - 1835008; }
    float4 v = reinterpret_cast<const float4*>(src)[li];
    f16x4 o = {(f16)v.x, (f16)v.y, (f16)v.z, (f16)v.w};
    reinterpret_cast<f16x4*>(out)[i] = o;
}

// ---------------- QKV GEMM: C[4096x3072] = X[4096x1024] * Wqkv^T ----------------
// R7: 3-deep pipelined K-loop. BK=32, 3 LDS buffers (ring t%3): while computing
// tile t, tile t+2 is being staged; tile t+1 is landing. One raw s_barrier per
// tile with counted s_waitcnt vmcnt(4) (never drains the queue in steady state).
__global__ __launch_bounds__(256, 3) void gemm_qkv(
    const f16* __restrict__ A, const f16* __restrict__ B,
    f16* __restrict__ outq, f16* __restrict__ outk, f16* __restrict__ outvt)
{
    __shared__ f16 As[3][128 * 32];
    __shared__ f16 Bs[3][128 * 32];
    const int tid = threadIdx.x;
    const int lane = tid & 63;
    const int wave = tid >> 6;
    const int wm = wave >> 1, wn = wave & 1;
    const int bm = blockIdx.y * 128, bn = blockIdx.x * 128;
    const int fr = lane & 15, fq = lane >> 4;

    const int srow = tid >> 2;                                    // 0..63
    const int su = (tid & 3) ^ (srow & 3) ^ ((srow >> 2) & 3);    // swizzled src 16B-unit
    const int uoff = (fq ^ (fr & 3) ^ ((fr >> 2) & 3)) * 8;       // lane-const read offset

    f32x4 acc[4][4] = {};

    auto stg = [&](int tt, int buf) {
        const int k0 = tt * 32;
        gload_lds16(&A[(bm + srow) * 1024 + k0 + su * 8],      &As[buf][tid * 8]);
        gload_lds16(&A[(bm + 64 + srow) * 1024 + k0 + su * 8], &As[buf][2048 + tid * 8]);
        gload_lds16(&B[(bn + srow) * 1024 + k0 + su * 8],      &Bs[buf][tid * 8]);
        gload_lds16(&B[(bn + 64 + srow) * 1024 + k0 + su * 8], &Bs[buf][2048 + tid * 8]);
    };

    auto step = [&](int t, int buf) {
        const int b2 = (buf + 2 >= 3) ? (buf - 1) : (buf + 2);
        if (t < 30) stg(t + 2, b2);
        f16x8 af[4], bf[4];
#pragma unroll
        for (int mt = 0; mt < 4; ++mt)
            af[mt] = *(const f16x8*)&As[buf][(wm * 64 + mt * 16 + fr) * 32 + uoff];
#pragma unroll
        for (int nt = 0; nt < 4; ++nt)
            bf[nt] = *(const f16x8*)&Bs[buf][(wn * 64 + nt * 16 + fr) * 32 + uoff];
        __builtin_amdgcn_s_setprio(1);
#pragma unroll
        for (int mt = 0; mt < 4; ++mt)
#pragma unroll
            for (int nt = 0; nt < 4; ++nt)
                acc[mt][nt] = MFMA16(af[mt], bf[nt], acc[mt][nt]);
        __builtin_amdgcn_s_setprio(0);
        if (t < 30) { asm volatile("s_waitcnt vmcnt(4)" ::: "memory"); }
        else        { asm volatile("s_waitcnt vmcnt(0)" ::: "memory"); }
        __builtin_amdgcn_s_barrier();
        __builtin_amdgcn_sched_barrier(0);
    };

    stg(0, 0);
    stg(1, 1);
    asm volatile("s_waitcnt vmcnt(4)" ::: "memory");
    __builtin_amdgcn_s_barrier();
    __builtin_amdgcn_sched_barrier(0);
#pragma unroll 1
    for (int tb = 0; tb < 30; tb += 3) {
        step(tb, 0);
        step(tb + 1, 1);
        step(tb + 2, 2);
    }
    step(30, 0);
    step(31, 1);

    const int x = blockIdx.x;
    if (x < 16) {
        // Q (x<8) or K block: uniform target, row-layout [bh][s][64]
        f16* base = (x < 8) ? outq : outk;
        const float scale = (x < 8) ? QSCALE : 1.0f;
        const int coloff = (x < 8) ? bn : (bn - 1024);
#pragma unroll
        for (int mt = 0; mt < 4; ++mt)
#pragma unroll
            for (int nt = 0; nt < 4; ++nt)
#pragma unroll
                for (int i = 0; i < 4; ++i) {
                    int row = bm + wm * 64 + mt * 16 + fq * 4 + i;  // (s*2+b)
                    int col = coloff + wn * 64 + nt * 16 + fr;      // 0..1023
                    int s = row >> 1, b = row & 1;
                    int h = col >> 6, dk = col & 63;
                    base[((b * 16 + h) * 2048 + s) * 64 + dk] = (f16)(acc[mt][nt][i] * scale);
                }
    } else {
        // V block: LDS transpose (2 passes over wn halves) -> vt[bh][dk][s]
        const int xb = x - 16;              // 0..7
        const int s0 = bm >> 1;             // 64-aligned s base
        f16* Ts = &As[0][0];                // [128][76] = 9728 f16 (fits in As[3][4096])
#pragma unroll
        for (int p = 0; p < 2; ++p) {
            __syncthreads();
            if (wn == p) {
#pragma unroll
                for (int mt = 0; mt < 4; ++mt)
#pragma unroll
                    for (int nt = 0; nt < 4; ++nt)
#pragma unroll
                        for (int i = 0; i < 4; ++i) {
                            int row = wm * 64 + mt * 16 + fq * 4 + i;  // 0..127 local
                            int cl = nt * 16 + fr;                     // 0..63 local col
                            Ts[(cl * 2 + (row & 1)) * 76 + (row >> 1)] = (f16)acc[mt][nt][i];
                        }
            }
            __syncthreads();
            const int h = xb * 2 + p;
            const int sj = tid & 7;
#pragma unroll
            for (int it = 0; it < 4; ++it) {
                int idx = (tid >> 3) + it * 32;     // 0..127
                int bsel = idx & 1, dk = idx >> 1;  // b, dk(=cl)
                f16x8 v = *(const f16x8*)&Ts[(dk * 2 + bsel) * 76 + sj * 8];
                *(f16x8*)&outvt[((bsel * 16 + h) * 64 + dk) * 2048 + s0 + sj * 8] = v;
            }
        }
    }
}

// ---------------- Flash attention (causal) — R11: R10 + 3-ring counted-vmcnt K/V ----------
// Exact R10 compute (8 waves, A/B tile split, LDS-P round-trip, XCD swizzle).
// NEW (T3+T4, proven on gemm_qkv in R7): replace per-chunk __syncthreads (full
// vmcnt(0)+lgkm(0) drain, depth-1 prefetch) with a 3-buffer K/V ring, raw
// s_barrier, and counted s_waitcnt vmcnt(2): chunk kc+2's 2 loads stay in flight
// across the barrier; only kc+1's must have landed. Ring hazard: slot (kc+2)%3
// last read at iteration kc-1, completed before the barrier that precedes this
// stage issue. LDS 66KB is free: the 512-block grid caps residency at 2 blocks/CU.
// T5 setprio around both MFMA clusters (attn has wave role-split, m191).
__global__ __launch_bounds__(512) void attn_kernel(
    const f16* __restrict__ qg, const f16* __restrict__ kg,
    const f16* __restrict__ vtg, f16* __restrict__ attn)
{
    __shared__ f16 Ks[3][64 * 64];
    __shared__ f16 Vs[3][64 * 64];
    __shared__ f16 plds[8][16 * 72];
    const int tid = threadIdx.x;
    const int lane = tid & 63;
    const int wave = tid >> 6;      // 0..7

    // XCD-aware remap (bijective on 512): XCD = w&7 == bh&7
    const int w = blockIdx.x + (blockIdx.y << 4);
    const int xcd = w & 7;
    const int idx = w >> 3;                  // 0..63
    const int bh = xcd + ((idx & 3) << 3);   // 0..31, bh%8 == xcd
    const int qpair = idx >> 2;              // 0..15, longest stream first

    const int b = bh >> 4, h = bh & 15;
    const int fr = lane & 15, fq = lane >> 4;

    const bool isB = wave < 4;
    const int w4 = wave & 3;
    const int qrow = (isB ? (31 - qpair) : qpair) * 64 + w4 * 16;  // wave's 16-row base
    const int nB = 32 - qpair;              // chunks streamed by the block (>=17)
    const int nK = isB ? nB : (qpair + 1);  // chunks this wave computes

    const f16* Q  = qg  + bh * 2048 * 64;
    const f16* K  = kg  + bh * 2048 * 64;
    const f16* VT = vtg + bh * 64 * 2048;
    f16* P = plds[wave];

    const int sr = tid >> 3;                // 0..63: full 64-row chunk in one issue
    const int scu = (tid & 7) ^ (sr & 7);

    f16x8 aq0 = *(const f16x8*)&Q[(qrow + fr) * 64 + fq * 8];
    f16x8 aq1 = *(const f16x8*)&Q[(qrow + fr) * 64 + 32 + fq * 8];

    f32x4 o[4] = {};
    float l[4] = {};

    auto stage = [&](int kc, int buf) {
        const int kb = kc * 64;
        gload_lds16(&K[(kb + sr) * 64 + scu * 8], &Ks[buf][tid * 8]);
        gload_lds16(&VT[sr * 2048 + kb + scu * 8], &Vs[buf][tid * 8]);
    };

    auto compute = [&](int kb, const f16* Ksb, const f16* Vsb, bool domask) {
        f32x4 sc[4] = {};
        __builtin_amdgcn_s_setprio(1);
#pragma unroll
        for (int ct = 0; ct < 4; ++ct) {
            int r = ct * 16 + fr;
            f16x8 b0 = *(const f16x8*)&Ksb[r * 64 + ((fq ^ (r & 7)) * 8)];
            f16x8 b1 = *(const f16x8*)&Ksb[r * 64 + (((4 + fq) ^ (r & 7)) * 8)];
            sc[ct] = MFMA16(aq0, b0, sc[ct]);
            sc[ct] = MFMA16(aq1, b1, sc[ct]);
        }
        __builtin_amdgcn_s_setprio(0);
        if (domask) {
#pragma unroll
            for (int ct = 0; ct < 4; ++ct) {
                int kcol = kb + ct * 16 + fr;
#pragma unroll
                for (int i = 0; i < 4; ++i)
                    if (kcol > qrow + fq * 4 + i) sc[ct][i] = -1e30f;
            }
        }
#pragma unroll
        for (int i = 0; i < 4; ++i) {
            float p0 = __builtin_amdgcn_exp2f(sc[0][i]);
            float p1 = __builtin_amdgcn_exp2f(sc[1][i]);
            float p2 = __builtin_amdgcn_exp2f(sc[2][i]);
            float p3 = __builtin_amdgcn_exp2f(sc[3][i]);
            l[i] += (p0 + p1) + (p2 + p3);
            P[(fq * 4 + i) * 72 + fr]      = (f16)p0;
            P[(fq * 4 + i) * 72 + 16 + fr] = (f16)p1;
            P[(fq * 4 + i) * 72 + 32 + fr] = (f16)p2;
            P[(fq * 4 + i) * 72 + 48 + fr] = (f16)p3;
        }
        f16x8 ap0 = *(const f16x8*)&P[fr * 72 + fq * 8];
        f16x8 ap1 = *(const f16x8*)&P[fr * 72 + 32 + fq * 8];
        __builtin_amdgcn_s_setprio(1);
#pragma unroll
        for (int nt = 0; nt < 4; ++nt) {
            int dk = nt * 16 + fr;
            f16x8 bv0 = *(const f16x8*)&Vsb[dk * 64 + ((fq ^ (dk & 7)) * 8)];
            f16x8 bv1 = *(const f16x8*)&Vsb[dk * 64 + (((4 + fq) ^ (dk & 7)) * 8)];
            o[nt] = MFMA16(ap0, bv0, o[nt]);
            o[nt] = MFMA16(ap1, bv1, o[nt]);
        }
        __builtin_amdgcn_s_setprio(0);
    };

    // prologue: stage 0,1; wait for 0 (1 may stay in flight across the barrier)
    stage(0, 0);
    stage(1, 1);
    asm volatile("s_waitcnt vmcnt(2)" ::: "memory");
    __builtin_amdgcn_s_barrier();
    __builtin_amdgcn_sched_barrier(0);

    int cur = 0;
#pragma unroll 1
    for (int kc = 0; kc < nB; ++kc) {
        if (kc + 2 < nB) {
            int b2 = cur + 2; if (b2 >= 3) b2 -= 3;
            stage(kc + 2, b2);
        }
        if (kc < nK) compute(kc * 64, Ks[cur], Vs[cur], kc * 64 + 63 > qrow);
        if (kc + 2 < nB) { asm volatile("s_waitcnt vmcnt(2)" ::: "memory"); }
        else             { asm volatile("s_waitcnt vmcnt(0)" ::: "memory"); }
        __builtin_amdgcn_s_barrier();
        __builtin_amdgcn_sched_barrier(0);
        if (++cur == 3) cur = 0;
    }

#pragma unroll
    for (int i = 0; i < 4; ++i) {
        float rs = l[i];
        rs += __shfl_xor(rs, 1);
        rs += __shfl_xor(rs, 2);
        rs += __shfl_xor(rs, 4);
        rs += __shfl_xor(rs, 8);
        float inv = __builtin_amdgcn_rcpf(rs);
        int srow = qrow + fq * 4 + i;
#pragma unroll
        for (int nt = 0; nt < 4; ++nt)
            attn[(srow * 2 + b) * 1024 + h * 64 + nt * 16 + fr] = (f16)(o[nt][i] * inv);
    }
}

// ---------------- Out GEMM: out[4096x1024] = A[4096x1024] * Wout^T + bias ----------------
// Same 3-deep pipelined structure as gemm_qkv (BK=32, ring of 3, counted vmcnt).
__global__ __launch_bounds__(256) void gemm_out(
    const f16* __restrict__ A, const f16* __restrict__ B,
    const float* __restrict__ bias, float* __restrict__ out)
{
    __shared__ f16 As[3][128 * 32];
    __shared__ f16 Bs[3][64 * 32];
    const int tid = threadIdx.x;
    const int lane = tid & 63;
    const int wave = tid >> 6;
    const int wm = wave >> 1, wn = wave & 1;
    const int bm = blockIdx.y * 128, bn = blockIdx.x * 64;
    const int fr = lane & 15, fq = lane >> 4;

    const int srow = tid >> 2;                                    // 0..63
    const int su = (tid & 3) ^ (srow & 3) ^ ((srow >> 2) & 3);
    const int uoff = (fq ^ (fr & 3) ^ ((fr >> 2) & 3)) * 8;

    f32x4 acc[4][2] = {};

    auto stg = [&](int tt, int buf) {
        const int k0 = tt * 32;
        gload_lds16(&A[(bm + srow) * 1024 + k0 + su * 8],      &As[buf][tid * 8]);
        gload_lds16(&A[(bm + 64 + srow) * 1024 + k0 + su * 8], &As[buf][2048 + tid * 8]);
        gload_lds16(&B[(bn + srow) * 1024 + k0 + su * 8],      &Bs[buf][tid * 8]);
    };

    auto step = [&](int t, int buf) {
        const int b2 = (buf + 2 >= 3) ? (buf - 1) : (buf + 2);
        if (t < 30) stg(t + 2, b2);
        f16x8 af[4], bf[2];
#pragma unroll
        for (int mt = 0; mt < 4; ++mt)
            af[mt] = *(const f16x8*)&As[buf][(wm * 64 + mt * 16 + fr) * 32 + uoff];
#pragma unroll
        for (int nt = 0; nt < 2; ++nt)
            bf[nt] = *(const f16x8*)&Bs[buf][(wn * 32 + nt * 16 + fr) * 32 + uoff];
        __builtin_amdgcn_s_setprio(1);
#pragma unroll
        for (int mt = 0; mt < 4; ++mt)
#pragma unroll
            for (int nt = 0; nt < 2; ++nt)
                acc[mt][nt] = MFMA16(af[mt], bf[nt], acc[mt][nt]);
        __builtin_amdgcn_s_setprio(0);
        if (t < 30) { asm volatile("s_waitcnt vmcnt(3)" ::: "memory"); }
        else        { asm volatile("s_waitcnt vmcnt(0)" ::: "memory"); }
        __builtin_amdgcn_s_barrier();
        __builtin_amdgcn_sched_barrier(0);
    };

    stg(0, 0);
    stg(1, 1);
    asm volatile("s_waitcnt vmcnt(3)" ::: "memory");
    __builtin_amdgcn_s_barrier();
    __builtin_amdgcn_sched_barrier(0);
#pragma unroll 1
    for (int tb = 0; tb < 30; tb += 3) {
        step(tb, 0);
        step(tb + 1, 1);
        step(tb + 2, 2);
    }
    step(30, 0);
    step(31, 1);

#pragma unroll
    for (int mt = 0; mt < 4; ++mt)
#pragma unroll
        for (int nt = 0; nt < 2; ++nt)
#pragma unroll
            for (int i = 0; i < 4; ++i) {
                int row = bm + wm * 64 + mt * 16 + fq * 4 + i;
                int col = bn + wn * 32 + nt * 16 + fr;
                out[row * 1024 + col] = acc[mt][nt][i] + bias[col];
            }
}

extern "C" void kernel_launch(void* const* d_in, const int* in_sizes, int n_in,
                              void* d_out, int out_size, void* d_ws, size_t ws_size,
                              hipStream_t stream)
{
    const float* x     = (const float*)d_in[0];
    const float* w_qkv = (const float*)d_in[1];
    const float* w_out = (const float*)d_in[2];
    const float* b_out = (const float*)d_in[3];
    float* out = (float*)d_out;

    char* ws = (char*)d_ws;
    f16* xh  = (f16*)(ws);
    f16* wqh = (f16*)(ws + 8388608);
    f16* woh = (f16*)(ws + 14680064);
    f16* qh  = (f16*)(ws + 16777216);
    f16* kh  = (f16*)(ws + 25165824);
    f16* vt  = (f16*)(ws + 33554432);
    f16* ah  = (f16*)(ws + 41943040);

    cast_all<<<8192, 256, 0, stream>>>(x, w_qkv, w_out, xh);
    gemm_qkv<<<dim3(24, 32), 256, 0, stream>>>(xh, wqh, qh, kh, vt);
    attn_kernel<<<dim3(16, 32), 512, 0, stream>>>(qh, kh, vt, ah);
    gemm_out<<<dim3(16, 32), 256, 0, stream>>>(ah, woh, b_out, out);
}